// Round 6
// baseline (186.608 us; speedup 1.0000x reference)
//
#include <hip/hip_runtime.h>
#include <cstdint>
#include <cstddef>

// Problem constants (fixed by the reference)
#define B_      32
#define N_      8400
#define C_      80
#define NC      672000        // N_*C_
#define NCV4    168000        // NC/4
#define NBINS   4096
#define TOPK    1024
#define MAXDET  300
#define CANDCAP 4096
#define NSLICE  16
#define SLICE_V4 10500        // NCV4 / NSLICE
#define NBKT    8             // score bins 4088..4095 (all x in [0.998..1))
#define SEGB    64            // per-(batch,bucket,slice) cap (mean 10.25, 17 sigma)
#define BSORT   256           // per-bucket cap (mean 164, 7.2 sigma)
#define MTIGHT  2048          // nms_direct LDS key cap (M mean 1312, 20 sigma)
#define CAND_CAP 256          // per-class cap (mean 16.4, 38 sigma)
#define NMSD_CPB 4            // classes (=waves) per nms_direct block

// Static stage threshold: score >= 4088/4096 = 0.998046875.
// Expected candidates/batch = 672000*8/4096 = 1312 (sd ~36). Bucket = bin-4088
// partitions candidates into 8 ORDER-DISJOINT groups (floor is monotone, float
// bits are monotone): buckets concatenated 7..0 == exact lax.top_k order
// (score desc, index asc via key low bits). pos(key) = base(bucket) +
// #{greater keys in bucket}. Violating inputs take the exact in-kernel
// fallback in finalize (never on bench input).
#define STAGE_THRESH 0.998046875f

// Workspace layout (bytes)
#define WS_SEGKEYS  0           // 32*8*16*64*8 = 2097152
#define WS_SEGCNT   2097152     // 32*8*16*4    = 16384
#define WS_TOPSCORE 2113536     // 32*1024*4    = 131072
#define WS_TOPBOX   2244608     // 32*1024*16   = 524288
#define WS_CLSV     2768896     // 32*1024*1    = 32768   (0x80|class)
#define WS_KEEP     2801664     // 32*1024*1    = 32768

// Output layout (float32, concatenated): boxes[32][300][4], scores[32][300],
// labels[32][300], n_valid[32]
#define OUT_SCORES  38400
#define OUT_LABELS  48000
#define OUT_NVALID  57600

// ---------------------------------------------------------------------------
// K1: single-pass filter+stage into PRIVATE per-(batch,bucket,slice) segments.
// key = (bits(v)<<32) | ~flat_idx. Memory-bound: 86 MB ~= 14.5 us (roofline).
__global__ __launch_bounds__(256) void stage_kernel(const float4* __restrict__ scores4,
                                                    unsigned* __restrict__ segCnt,
                                                    unsigned long long* __restrict__ segKeys) {
    __shared__ unsigned lcnt[NBKT];
    int b = blockIdx.x, sl = blockIdx.y, tid = threadIdx.x;
    if (tid < NBKT) lcnt[tid] = 0;
    __syncthreads();
    const float4* s = scores4 + (size_t)b * NCV4 + (size_t)sl * SLICE_V4;
    for (int i = tid; i < SLICE_V4; i += 256) {
        float4 v = s[i];
        float c[4] = {v.x, v.y, v.z, v.w};
        unsigned flat0 = ((unsigned)sl * SLICE_V4 + (unsigned)i) * 4u;
        #pragma unroll
        for (int kc = 0; kc < 4; ++kc) {
            float x = (c[kc] > 0.001f) ? c[kc] : 0.0f;
            if (x >= STAGE_THRESH) {
                int bin = (int)(x * 4096.0f);             // exact: x * 2^12
                bin = bin > (NBINS - 1) ? (NBINS - 1) : bin;
                int bkt = bin - 4088;                      // 0..7
                unsigned p = atomicAdd(&lcnt[bkt], 1u);
                if (p < (unsigned)SEGB)
                    segKeys[(((size_t)(b * NBKT + bkt)) * NSLICE + sl) * SEGB + p] =
                        ((unsigned long long)__float_as_uint(x) << 32) |
                        (unsigned long long)(0xFFFFFFFFu - (flat0 + kc));
            }
        }
    }
    __syncthreads();
    if (tid < NBKT) segCnt[(b * NBKT + tid) * NSLICE + sl] = lcnt[tid];
}

// ---------------------------------------------------------------------------
// K2: nms_direct — replaces select+nms (one fewer launch). grid (B,20) x 256:
// 4 waves/block, wave w owns class 4*g+w. Block stages the batch's M keys
// (SoA lo/hi) into LDS once; each wave: register extraction of its class,
// per-bucket rank -> global position (pos = base + #greater-in-bucket ==
// exact lax.top_k position), writes topScore/topBox/clsv AND keep at its
// class-owned positions (classes partition [0,1024) => full coverage, no
// pre-zeroing), then mask-greedy NMS (r5-proven, m<=64; LDS-iterative for
// m>64 — never on bench). Invalid stage output: all blocks bail; finalize's
// embedded exact fallback handles the batch end-to-end.
__global__ __launch_bounds__(256) void nms_direct_kernel(
        const unsigned long long* __restrict__ segKeys,
        const unsigned* __restrict__ segCnt,
        const float4* __restrict__ boxes4,
        float* __restrict__ topScore,
        float4* __restrict__ topBox4,
        unsigned char* __restrict__ clsv,
        unsigned char* __restrict__ keepB) {
    __shared__ unsigned sCnt[NBKT * NSLICE];          // 512 B
    __shared__ unsigned sPref[NBKT * NSLICE];         // 512 B (flat kbuf offs)
    __shared__ unsigned sBStart[NBKT], sBCnt[NBKT], sBase[NBKT];
    __shared__ unsigned kLo[MTIGHT], kHi[MTIGHT];     // 16 KB SoA keys
    __shared__ unsigned short wCand[NMSD_CPB][CAND_CAP];   // 2 KB
    __shared__ unsigned short wPos[NMSD_CPB][CAND_CAP];    // 2 KB (0xFFFF inv)
    __shared__ unsigned short wOPos[NMSD_CPB][CAND_CAP];   // 2 KB
    __shared__ float wy1[NMSD_CPB][CAND_CAP], wx1[NMSD_CPB][CAND_CAP];
    __shared__ float wy2[NMSD_CPB][CAND_CAP], wx2[NMSD_CPB][CAND_CAP];
    __shared__ float war[NMSD_CPB][CAND_CAP];              // 20 KB
    __shared__ unsigned char wSup[NMSD_CPB][CAND_CAP];     // 1 KB

    int b = blockIdx.x, g = blockIdx.y, tid = threadIdx.x;
    int lane = tid & 63, wave = tid >> 6;

    // P0: counts -> LDS; redundant lockstep validity + bucket sums.
    if (tid < NBKT * NSLICE) sCnt[tid] = segCnt[b * NBKT * NSLICE + tid];
    __syncthreads();
    unsigned M = 0; int valid = 1; unsigned bsumR[NBKT];
    #pragma unroll
    for (int t = 0; t < NBKT; ++t) {
        unsigned s2 = 0, mx = 0;
        #pragma unroll
        for (int sl = 0; sl < NSLICE; ++sl) {
            unsigned v = sCnt[t * NSLICE + sl];
            s2 += v; mx = v > mx ? v : mx;
        }
        if (mx > (unsigned)SEGB || s2 > (unsigned)BSORT) valid = 0;
        bsumR[t] = s2; M += s2;
    }
    if (M < (unsigned)TOPK || M > (unsigned)MTIGHT) valid = 0;
    if (!valid) return;                 // uniform; finalize fallback takes over
    if (tid < NBKT * NSLICE) {
        unsigned a = 0;
        for (int i = 0; i < tid; ++i) a += sCnt[i];
        sPref[tid] = a;
    }
    if (tid < NBKT) {
        unsigned st = 0, ba = 0;
        for (int t = 0; t < tid; ++t) st += bsumR[t];
        for (int t = tid + 1; t < NBKT; ++t) ba += bsumR[t];
        sBStart[tid] = st; sBCnt[tid] = bsumR[tid]; sBase[tid] = ba;
    }
    __syncthreads();

    // P1: stage M keys -> LDS SoA. 32 segments/wave, predicated coalesced.
    #pragma unroll 4
    for (int s32 = 0; s32 < 32; ++s32) {
        int seg = wave * 32 + s32;
        unsigned k = sCnt[seg], off = sPref[seg];
        const unsigned long long* src =
            segKeys + ((size_t)b * NBKT * NSLICE + seg) * SEGB;
        if ((unsigned)lane < k) {
            unsigned long long v = src[lane];
            kLo[off + lane] = (unsigned)v;
            kHi[off + lane] = (unsigned)(v >> 32);
        }
    }
    __syncthreads();    // waves diverge below; no block barriers after this

    int c = g * NMSD_CPB + wave;                       // 0..79
    float offc = (float)c * 4096.0f;                   // exact
    // P2: extraction — stream all M keys, ballot-compact class-c hits.
    unsigned mc = 0;
    for (unsigned r0 = 0; r0 < M; r0 += 64) {
        unsigned i = r0 + lane; bool match = false;
        if (i < M) {
            unsigned flat = ~kLo[i];
            if (flat >= (unsigned)NC) flat = 0;        // defensive (parity r3)
            unsigned cls = flat % (unsigned)C_;
            match = (cls == (unsigned)c);
        }
        unsigned long long mb = __ballot(match);
        int pre = __popcll(mb & ((1ull << lane) - 1ull));
        if (match) {
            unsigned s = mc + pre;
            if (s < (unsigned)CAND_CAP) wCand[wave][s] = (unsigned short)i;
        }
        mc += (unsigned)__popcll(mb);
    }
    if (mc > (unsigned)CAND_CAP) mc = CAND_CAP;
    __threadfence_block();
    if (mc == 0) return;                               // wave-level exit OK

    if (mc <= 64) {
        // ---- fast path: cand j lives in lane j.
        unsigned short mypos = 0xFFFF;
        float y1 = 0, x1 = 0, y2 = 0, x2 = 0, ar = 0;
        if (lane < (int)mc) {
            unsigned i = wCand[wave][lane];
            unsigned lo = kLo[i], hi = kHi[i];
            float sc = __uint_as_float(hi);
            int bin = (int)(sc * 4096.0f);
            bin = bin > (NBINS - 1) ? (NBINS - 1) : bin;
            int bkt = bin - 4088;
            bkt = bkt < 0 ? 0 : (bkt > 7 ? 7 : bkt);   // defensive
            unsigned st = sBStart[bkt], nb = sBCnt[bkt], r = 0;
            for (unsigned t = 0; t < nb; ++t) {
                unsigned oh = kHi[st + t];
                if (oh > hi || (oh == hi && kLo[st + t] > lo)) ++r;
            }
            unsigned pos = sBase[bkt] + r;
            unsigned flat = ~lo;
            if (flat >= (unsigned)NC) flat = 0;
            unsigned bi = flat / (unsigned)C_;
            if (pos < (unsigned)TOPK) {
                float4 tb = boxes4[(size_t)b * N_ + bi];
                topScore[b * TOPK + pos] = sc;
                topBox4[(size_t)b * TOPK + pos] = tb;
                clsv[(size_t)b * TOPK + pos] = (unsigned char)(0x80u | c);
                mypos = (unsigned short)pos;
                y1 = tb.x + offc; x1 = tb.y + offc;
                y2 = tb.z + offc; x2 = tb.w + offc;
                ar = __fmul_rn((x2 - x1) + 1.0f, (y2 - y1) + 1.0f);
            }
        }
        wPos[wave][lane] = mypos;
        __threadfence_block();
        bool vme = (lane < (int)mc) && (mypos != 0xFFFF);
        int srank = 0;
        for (unsigned k2 = 0; k2 < mc; ++k2) {
            unsigned short pk = wPos[wave][k2];
            if (pk != 0xFFFF && pk < mypos) ++srank;
        }
        int mc2 = (int)__popcll(__ballot(vme));
        if (vme) {
            wy1[wave][srank] = y1; wx1[wave][srank] = x1;
            wy2[wave][srank] = y2; wx2[wave][srank] = x2;
            war[wave][srank] = ar; wOPos[wave][srank] = mypos;
        }
        __threadfence_block();
        float Y1 = 0, X1 = 0, Y2 = 0, X2 = 0, AR = 0; unsigned short OP = 0;
        if (lane < mc2) {
            Y1 = wy1[wave][lane]; X1 = wx1[wave][lane];
            Y2 = wy2[wave][lane]; X2 = wx2[wave][lane];
            AR = war[wave][lane]; OP = wOPos[wave][lane];
        }
        // mask-greedy (r5-proven): position order == score-desc order.
        unsigned long long sup = 0, keepm = 0;
        for (int i = 0; i < mc2; ++i) {
            if ((sup >> i) & 1ull) continue;           // uniform branch
            keepm |= 1ull << i;
            float cy1 = __shfl(Y1, i, 64), cx1 = __shfl(X1, i, 64);
            float cy2 = __shfl(Y2, i, 64), cx2 = __shfl(X2, i, 64);
            float ca  = __shfl(AR, i, 64);
            bool over = false;
            if (lane < mc2 && lane > i) {
                float yy1 = fmaxf(cy1, Y1), xx1 = fmaxf(cx1, X1);
                float yy2 = fminf(cy2, Y2), xx2 = fminf(cx2, X2);
                float w2 = fmaxf(0.0f, (xx2 - xx1) + 1.0f);
                float h2 = fmaxf(0.0f, (yy2 - yy1) + 1.0f);
                float inter = __fmul_rn(w2, h2);
                float denom = (ca + AR) - inter;
                over = inter / denom > 0.7f;
            }
            sup |= __ballot(over);
        }
        if (lane < mc2)
            keepB[(size_t)b * TOPK + OP] = (unsigned char)((keepm >> lane) & 1ull);
    } else {
        // ---- slow path (mc>64; never on bench): strided rank + LDS greedy.
        for (unsigned j = lane; j < mc; j += 64) {
            unsigned i = wCand[wave][j];
            unsigned lo = kLo[i], hi = kHi[i];
            float sc = __uint_as_float(hi);
            int bin = (int)(sc * 4096.0f);
            bin = bin > (NBINS - 1) ? (NBINS - 1) : bin;
            int bkt = bin - 4088;
            bkt = bkt < 0 ? 0 : (bkt > 7 ? 7 : bkt);
            unsigned st = sBStart[bkt], nb = sBCnt[bkt], r = 0;
            for (unsigned t = 0; t < nb; ++t) {
                unsigned oh = kHi[st + t];
                if (oh > hi || (oh == hi && kLo[st + t] > lo)) ++r;
            }
            unsigned pos = sBase[bkt] + r;
            unsigned flat = ~lo;
            if (flat >= (unsigned)NC) flat = 0;
            unsigned bi = flat / (unsigned)C_;
            unsigned short ps = 0xFFFF;
            if (pos < (unsigned)TOPK) {
                float4 tb = boxes4[(size_t)b * N_ + bi];
                topScore[b * TOPK + pos] = sc;
                topBox4[(size_t)b * TOPK + pos] = tb;
                clsv[(size_t)b * TOPK + pos] = (unsigned char)(0x80u | c);
                ps = (unsigned short)pos;
            }
            wPos[wave][j] = ps;
        }
        // pad unused wPos slots so rank scans see sentinels
        for (unsigned j = mc + lane; j < (unsigned)CAND_CAP; j += 64)
            wPos[wave][j] = 0xFFFF;
        __threadfence_block();
        int mc2 = 0;
        for (unsigned k2 = 0; k2 < mc; ++k2)
            if (wPos[wave][k2] != 0xFFFF) ++mc2;
        for (unsigned j = lane; j < mc; j += 64) {
            unsigned short pj = wPos[wave][j];
            if (pj != 0xFFFF) {
                int sr = 0;
                for (unsigned k2 = 0; k2 < mc; ++k2) {
                    unsigned short pk = wPos[wave][k2];
                    if (pk != 0xFFFF && pk < pj) ++sr;
                }
                unsigned i = wCand[wave][j];
                unsigned flat = ~kLo[i];
                if (flat >= (unsigned)NC) flat = 0;
                unsigned bi = flat / (unsigned)C_;
                float4 tb = boxes4[(size_t)b * N_ + bi];
                float y1 = tb.x + offc, x1 = tb.y + offc;
                float y2 = tb.z + offc, x2 = tb.w + offc;
                wy1[wave][sr] = y1; wx1[wave][sr] = x1;
                wy2[wave][sr] = y2; wx2[wave][sr] = x2;
                war[wave][sr] = __fmul_rn((x2 - x1) + 1.0f, (y2 - y1) + 1.0f);
                wOPos[wave][sr] = pj; wSup[wave][sr] = 0;
            }
        }
        __threadfence_block();
        int cur = 0;
        while (cur < mc2) {
            float cy1 = wy1[wave][cur], cx1 = wx1[wave][cur];
            float cy2 = wy2[wave][cur], cx2 = wx2[wave][cur];
            float ca = war[wave][cur];
            for (int j = cur + 1 + lane; j < mc2; j += 64) {
                if (!wSup[wave][j]) {
                    float yy1 = fmaxf(cy1, wy1[wave][j]), xx1 = fmaxf(cx1, wx1[wave][j]);
                    float yy2 = fminf(cy2, wy2[wave][j]), xx2 = fminf(cx2, wx2[wave][j]);
                    float w2 = fmaxf(0.0f, (xx2 - xx1) + 1.0f);
                    float h2 = fmaxf(0.0f, (yy2 - yy1) + 1.0f);
                    float inter = __fmul_rn(w2, h2);
                    float denom = (ca + war[wave][j]) - inter;
                    if (inter / denom > 0.7f) wSup[wave][j] = 1;
                }
            }
            __threadfence_block();
            int nxt = mc2;
            for (int j = cur + 1 + lane; j < mc2; j += 64)
                if (!wSup[wave][j]) { nxt = j; break; }
            for (int o = 32; o > 0; o >>= 1) {
                int other = __shfl_xor(nxt, o, 64);
                nxt = nxt < other ? nxt : other;
            }
            cur = nxt;
        }
        for (int j = lane; j < mc2; j += 64)
            keepB[(size_t)b * TOPK + wOPos[wave][j]] = wSup[wave][j] ? 0 : 1;
    }
}

// ---------------------------------------------------------------------------
// K3: finalize. Fast path (valid stage output): r3's 2-barrier ballot/popcount
// scan over keep + outputs. Invalid: embedded EXACT per-batch fallback (the
// round-5 fused body, bench-verified absmax=0) does select+NMS+finalize
// in-block from raw inputs. Validity predicate matches nms_direct's exactly.
__global__ __launch_bounds__(1024) void finalize_kernel(
        const float4* __restrict__ scores4,
        const unsigned long long* __restrict__ segKeys,
        const unsigned* __restrict__ segCnt,
        const float4* __restrict__ boxes4,
        const float* __restrict__ topScore,
        const float4* __restrict__ topBox4,
        const unsigned char* __restrict__ clsv,
        const unsigned char* __restrict__ keepB,
        float* __restrict__ out) {
    __shared__ unsigned scnt2[NBKT * NSLICE];
    __shared__ int wsum[16];
    __shared__ int sel[MAXDET];
    // fallback-only storage
    __shared__ unsigned bsum[NBKT];
    __shared__ unsigned spref2[NBKT][NSLICE];
    __shared__ float   sScore[TOPK];
    __shared__ int     sBoxIdx[TOPK];
    __shared__ __align__(16) unsigned char sClsv[TOPK];
    __shared__ float4  sBox[TOPK];
    __shared__ unsigned char sKeep[TOPK];
    __shared__ unsigned short sposW[16][BSORT];
    __shared__ unsigned char  supW[16][BSORT];
    __shared__ int s_cut;
    __shared__ unsigned s_scnt;
    __shared__ __align__(16) char upool[49152];
    unsigned long long* kbuf = (unsigned long long*)upool;
    unsigned* fh = (unsigned*)(upool + 32768);

    int b = blockIdx.x, tid = threadIdx.x;
    int lane = tid & 63, wave = tid >> 6;

    if (tid < NBKT * NSLICE) scnt2[tid] = segCnt[b * NBKT * NSLICE + tid];
    __syncthreads();
    unsigned M = 0; int valid = 1; unsigned bsumR[NBKT];
    #pragma unroll
    for (int t = 0; t < NBKT; ++t) {
        unsigned s2 = 0, mx = 0;
        #pragma unroll
        for (int sl = 0; sl < NSLICE; ++sl) {
            unsigned v = scnt2[t * NSLICE + sl];
            s2 += v; mx = v > mx ? v : mx;
        }
        if (mx > (unsigned)SEGB || s2 > (unsigned)BSORT) valid = 0;
        bsumR[t] = s2; M += s2;
    }
    if (M < (unsigned)TOPK || M > (unsigned)MTIGHT) valid = 0;

    if (valid) {
        // ---- fast path: ballot/popcount scan over keep (r3-proven).
        int kp = keepB[(size_t)b * TOPK + tid];
        unsigned long long mb = __ballot(kp != 0);
        int wpre = __popcll(mb & ((1ull << lane) - 1ull));
        if (lane == 0) wsum[wave] = __popcll(mb);
        __syncthreads();
        int wbase = 0, nk = 0;
        #pragma unroll
        for (int t = 0; t < 16; ++t) {
            int v = wsum[t];
            if (t < wave) wbase += v;
            nk += v;
        }
        int kexcl = wbase + wpre;
        int sexcl = tid - kexcl;
        if (kp) {
            if (kexcl < MAXDET) sel[kexcl] = tid;
        } else {
            int slot2 = nk + sexcl;
            if (slot2 < MAXDET) sel[slot2] = tid;
        }
        __syncthreads();
        if (tid < MAXDET) {
            int p = sel[tid];
            float sc = (tid < nk) ? topScore[b * TOPK + p] : 0.0f;
            float4 tb = topBox4[(size_t)b * TOPK + p];
            float* ob = out + ((size_t)b * MAXDET + tid) * 4;
            ob[0] = tb.x; ob[1] = tb.y; ob[2] = tb.z; ob[3] = tb.w;
            out[OUT_SCORES + b * MAXDET + tid] = sc;
            out[OUT_LABELS + b * MAXDET + tid] =
                (float)(clsv[(size_t)b * TOPK + p] & 0x7f);
        }
        if (tid == 0) out[OUT_NVALID + b] = (float)(nk < MAXDET ? nk : MAXDET);
        return;
    }

    // ================== EXACT FALLBACK (round-5 fused body) =================
    if (tid < NBKT * NSLICE) {
        int bkt = tid >> 4, sl = tid & 15;
        unsigned acc = 0;
        for (int s2 = 0; s2 < sl; ++s2) acc += scnt2[bkt * NSLICE + s2];
        spref2[bkt][sl] = acc;
        if (sl == 0) bsum[bkt] = bsumR[bkt];
    }
    __syncthreads();
    // r5's internal validity (wider M cap) — its own exact histogram path
    // covers everything else.
    int valid2 = 1; unsigned M2c = 0;
    #pragma unroll
    for (int t = 0; t < NBKT; ++t) {
        unsigned s2 = 0, mx = 0;
        #pragma unroll
        for (int sl = 0; sl < NSLICE; ++sl) {
            unsigned v = scnt2[t * NSLICE + sl];
            s2 += v; mx = v > mx ? v : mx;
        }
        if (mx > (unsigned)SEGB || s2 > (unsigned)BSORT) valid2 = 0;
        M2c += s2;
    }
    if (M2c < (unsigned)TOPK || M2c > (unsigned)CANDCAP) valid2 = 0;

    if (valid2) {
        for (int seg = wave; seg < NBKT * NSLICE; seg += 16) {
            int bkt = seg >> 4, sl = seg & 15;
            unsigned c2 = scnt2[seg];
            if ((unsigned)lane < c2)
                kbuf[bkt * BSORT + spref2[bkt][sl] + lane] =
                    segKeys[(((size_t)(b * NBKT + bkt)) * NSLICE + sl) * SEGB + lane];
        }
        __syncthreads();
        int bkt = tid >> 7;
        unsigned n = bsum[bkt];
        unsigned base = 0;
        for (int t = bkt + 1; t < NBKT; ++t) base += bsum[t];
        if (base < (unsigned)TOPK && n > 0) {
            const unsigned long long* kb = kbuf + bkt * BSORT;
            int j0 = tid & 127, j1 = j0 + 128;
            unsigned long long k0 = (j0 < (int)n) ? kb[j0] : 0ull;
            unsigned long long k1 = (j1 < (int)n) ? kb[j1] : 0ull;
            unsigned r0 = 0, r1 = 0;
            for (unsigned i = 0; i < n; ++i) {
                unsigned long long ki = kb[i];
                r0 += (ki > k0); r1 += (ki > k1);
            }
            if (j0 < (int)n) {
                unsigned pos = base + r0;
                if (pos < (unsigned)TOPK) {
                    unsigned idx = 0xFFFFFFFFu - (unsigned)(k0 & 0xFFFFFFFFull);
                    if (idx >= (unsigned)NC) idx = 0;
                    unsigned bi = idx / (unsigned)C_;
                    sScore[pos] = __uint_as_float((unsigned)(k0 >> 32));
                    sClsv[pos] = (unsigned char)(0x80u | (idx - bi * (unsigned)C_));
                    sBoxIdx[pos] = (int)bi;
                }
            }
            if (j1 < (int)n) {
                unsigned pos = base + r1;
                if (pos < (unsigned)TOPK) {
                    unsigned idx = 0xFFFFFFFFu - (unsigned)(k1 & 0xFFFFFFFFull);
                    if (idx >= (unsigned)NC) idx = 0;
                    unsigned bi = idx / (unsigned)C_;
                    sScore[pos] = __uint_as_float((unsigned)(k1 >> 32));
                    sClsv[pos] = (unsigned char)(0x80u | (idx - bi * (unsigned)C_));
                    sBoxIdx[pos] = (int)bi;
                }
            }
        }
    } else {
        for (int i = tid; i < NBINS; i += 1024) fh[i] = 0;
        if (tid == 0) s_scnt = 0;
        __syncthreads();
        const float4* s = scores4 + (size_t)b * NCV4;
        for (int i = tid; i < NCV4; i += 1024) {
            float4 v = s[i];
            float c4[4] = {v.x, v.y, v.z, v.w};
            #pragma unroll
            for (int kc = 0; kc < 4; ++kc) {
                float x = (c4[kc] > 0.001f) ? c4[kc] : 0.0f;
                int bin = (int)(x * 4096.0f);
                bin = bin > (NBINS - 1) ? (NBINS - 1) : bin;
                atomicAdd(&fh[bin], 1u);
            }
        }
        __syncthreads();
        if (tid == 0) {
            unsigned acc = 0; int cb2 = 0;
            for (int bin = NBINS - 1; bin >= 0; --bin) {
                acc += fh[bin];
                if (acc >= (unsigned)TOPK) { cb2 = bin; break; }
            }
            s_cut = cb2;
        }
        __syncthreads();
        int cb = s_cut;
        for (int i = tid; i < NCV4; i += 1024) {
            float4 v = s[i];
            float c4[4] = {v.x, v.y, v.z, v.w};
            unsigned flat0 = (unsigned)i * 4u;
            #pragma unroll
            for (int kc = 0; kc < 4; ++kc) {
                float x = (c4[kc] > 0.001f) ? c4[kc] : 0.0f;
                int bin = (int)(x * 4096.0f);
                bin = bin > (NBINS - 1) ? (NBINS - 1) : bin;
                if (bin >= cb) {
                    unsigned p = atomicAdd(&s_scnt, 1u);
                    if (p < (unsigned)CANDCAP)
                        kbuf[p] = ((unsigned long long)__float_as_uint(x) << 32) |
                                  (unsigned long long)(0xFFFFFFFFu - (flat0 + kc));
                }
            }
        }
        __syncthreads();
        unsigned Mf = s_scnt; if (Mf > (unsigned)CANDCAP) Mf = CANDCAP;
        int S = (Mf <= 1024u) ? 1024 : (Mf <= 2048u ? 2048 : CANDCAP);
        for (int i = (int)Mf + tid; i < S; i += 1024) kbuf[i] = 0ull;
        __syncthreads();
        for (int kk = 2; kk <= S; kk <<= 1) {
            for (int j = kk >> 1; j > 0; j >>= 1) {
                for (int t = tid; t < S; t += 1024) {
                    int l = t ^ j;
                    if (l > t) {
                        unsigned long long a0 = kbuf[t], c0 = kbuf[l];
                        bool sw = ((t & kk) == 0) ? (a0 < c0) : (a0 > c0);
                        if (sw) { kbuf[t] = c0; kbuf[l] = a0; }
                    }
                }
                __syncthreads();
            }
        }
        for (int r = tid; r < TOPK; r += 1024) {
            unsigned long long key = kbuf[r];
            float sc = __uint_as_float((unsigned)(key >> 32));
            unsigned idx = 0xFFFFFFFFu - (unsigned)(key & 0xFFFFFFFFull);
            if (idx >= (unsigned)NC) idx = 0;
            unsigned bi = idx / (unsigned)C_;
            sScore[r] = sc;
            sClsv[r] = (unsigned char)((sc > 0.001f ? 0x80u : 0u) |
                                       (idx - bi * (unsigned)C_));
            sBoxIdx[r] = (int)bi;
        }
    }
    __syncthreads();
    sBox[tid] = boxes4[(size_t)b * N_ + sBoxIdx[tid]];
    sKeep[tid] = 0;
    __syncthreads();
    for (int c = wave; c < C_; c += 16) {
        unsigned target = 0x80u | (unsigned)c;
        unsigned d0 = ((const unsigned*)sClsv)[lane * 4 + 0];
        unsigned d1 = ((const unsigned*)sClsv)[lane * 4 + 1];
        unsigned d2 = ((const unsigned*)sClsv)[lane * 4 + 2];
        unsigned d3 = ((const unsigned*)sClsv)[lane * 4 + 3];
        unsigned mmask = 0; int cnt = 0;
        #pragma unroll
        for (int t = 0; t < 16; ++t) {
            unsigned d = (t < 4) ? d0 : (t < 8) ? d1 : (t < 12) ? d2 : d3;
            unsigned v = (d >> ((t & 3) * 8)) & 0xffu;
            if (v == target) { mmask |= (1u << t); ++cnt; }
        }
        int x = cnt;
        #pragma unroll
        for (int o = 1; o < 64; o <<= 1) {
            int y = __shfl_up(x, o, 64);
            if (lane >= o) x += y;
        }
        int pre = x - cnt;
        int m = __shfl(x, 63, 64);
        int slot = pre;
        #pragma unroll
        for (int t = 0; t < 16; ++t) {
            if ((mmask >> t) & 1u) {
                if (slot < BSORT) sposW[wave][slot] = (unsigned short)(lane * 16 + t);
                ++slot;
            }
        }
        int m2 = m < BSORT ? m : BSORT;
        __threadfence_block();
        float off = (float)c * 4096.0f;
        if (m2 <= 64) {
            float y1 = 0, x1 = 0, y2 = 0, x2 = 0, ar = 0; int p = 0;
            if (lane < m2) {
                p = sposW[wave][lane];
                float4 tb = sBox[p];
                y1 = tb.x + off; x1 = tb.y + off;
                y2 = tb.z + off; x2 = tb.w + off;
                ar = __fmul_rn((x2 - x1) + 1.0f, (y2 - y1) + 1.0f);
            }
            unsigned long long sup = 0, keepm = 0;
            for (int i = 0; i < m2; ++i) {
                if ((sup >> i) & 1ull) continue;
                keepm |= 1ull << i;
                float cy1 = __shfl(y1, i, 64), cx1 = __shfl(x1, i, 64);
                float cy2 = __shfl(y2, i, 64), cx2 = __shfl(x2, i, 64);
                float ca  = __shfl(ar, i, 64);
                bool over = false;
                if (lane < m2 && lane > i) {
                    float yy1 = fmaxf(cy1, y1), xx1 = fmaxf(cx1, x1);
                    float yy2 = fminf(cy2, y2), xx2 = fminf(cx2, x2);
                    float w2 = fmaxf(0.0f, (xx2 - xx1) + 1.0f);
                    float h2 = fmaxf(0.0f, (yy2 - yy1) + 1.0f);
                    float inter = __fmul_rn(w2, h2);
                    float denom = (ca + ar) - inter;
                    over = inter / denom > 0.7f;
                }
                sup |= __ballot(over);
            }
            if (lane < m2 && ((keepm >> lane) & 1ull)) sKeep[p] = 1;
        } else {
            for (int j = lane; j < m2; j += 64) supW[wave][j] = 0;
            __threadfence_block();
            int cur = 0;
            while (cur < m2) {
                int pc = sposW[wave][cur];
                if (lane == 0) sKeep[pc] = 1;
                float4 cb4 = sBox[pc];
                float cy1 = cb4.x + off, cx1 = cb4.y + off;
                float cy2 = cb4.z + off, cx2 = cb4.w + off;
                float ca = __fmul_rn((cx2 - cx1) + 1.0f, (cy2 - cy1) + 1.0f);
                for (int j = cur + 1 + lane; j < m2; j += 64) {
                    if (!supW[wave][j]) {
                        float4 tb = sBox[sposW[wave][j]];
                        float y1 = tb.x + off, x1 = tb.y + off;
                        float y2 = tb.z + off, x2 = tb.w + off;
                        float arj = __fmul_rn((x2 - x1) + 1.0f, (y2 - y1) + 1.0f);
                        float yy1 = fmaxf(cy1, y1), xx1 = fmaxf(cx1, x1);
                        float yy2 = fminf(cy2, y2), xx2 = fminf(cx2, x2);
                        float w2 = fmaxf(0.0f, (xx2 - xx1) + 1.0f);
                        float h2 = fmaxf(0.0f, (yy2 - yy1) + 1.0f);
                        float inter = __fmul_rn(w2, h2);
                        float denom = (ca + arj) - inter;
                        if (inter / denom > 0.7f) supW[wave][j] = 1;
                    }
                }
                __threadfence_block();
                int nxt = m2;
                for (int j = cur + 1 + lane; j < m2; j += 64)
                    if (!supW[wave][j]) { nxt = j; break; }
                for (int o = 32; o > 0; o >>= 1) {
                    int other = __shfl_xor(nxt, o, 64);
                    nxt = nxt < other ? nxt : other;
                }
                cur = nxt;
            }
        }
    }
    __syncthreads();
    int kp = sKeep[tid];
    unsigned long long mb = __ballot(kp != 0);
    int wpre = __popcll(mb & ((1ull << lane) - 1ull));
    if (lane == 0) wsum[wave] = __popcll(mb);
    __syncthreads();
    int wbase = 0, nk = 0;
    #pragma unroll
    for (int t = 0; t < 16; ++t) {
        int v = wsum[t];
        if (t < wave) wbase += v;
        nk += v;
    }
    int kexcl = wbase + wpre;
    int sexcl = tid - kexcl;
    if (kp) {
        if (kexcl < MAXDET) sel[kexcl] = tid;
    } else {
        int slot2 = nk + sexcl;
        if (slot2 < MAXDET) sel[slot2] = tid;
    }
    __syncthreads();
    if (tid < MAXDET) {
        int p = sel[tid];
        float sc = (tid < nk) ? sScore[p] : 0.0f;
        float4 tb = sBox[p];
        float* ob = out + ((size_t)b * MAXDET + tid) * 4;
        ob[0] = tb.x; ob[1] = tb.y; ob[2] = tb.z; ob[3] = tb.w;
        out[OUT_SCORES + b * MAXDET + tid] = sc;
        out[OUT_LABELS + b * MAXDET + tid] = (float)(sClsv[p] & 0x7f);
    }
    if (tid == 0) out[OUT_NVALID + b] = (float)(nk < MAXDET ? nk : MAXDET);
}

// ---------------------------------------------------------------------------
extern "C" void kernel_launch(void* const* d_in, const int* in_sizes, int n_in,
                              void* d_out, int out_size, void* d_ws, size_t ws_size,
                              hipStream_t stream) {
    const float* boxes  = (const float*)d_in[0];   // (32, 8400, 4)
    const float* scores = (const float*)d_in[1];   // (32, 8400, 80)
    float* out = (float*)d_out;
    char* ws = (char*)d_ws;

    unsigned long long* segKeys = (unsigned long long*)(ws + WS_SEGKEYS);
    unsigned* segCnt = (unsigned*)(ws + WS_SEGCNT);
    float* topScore = (float*)(ws + WS_TOPSCORE);
    float4* topBox4 = (float4*)(ws + WS_TOPBOX);
    unsigned char* clsv = (unsigned char*)(ws + WS_CLSV);
    unsigned char* keepB = (unsigned char*)(ws + WS_KEEP);

    const float4* scores4 = (const float4*)scores;
    const float4* boxes4  = (const float4*)boxes;

    stage_kernel<<<dim3(B_, NSLICE), 256, 0, stream>>>(scores4, segCnt, segKeys);
    nms_direct_kernel<<<dim3(B_, C_ / NMSD_CPB), 256, 0, stream>>>(
        segKeys, segCnt, boxes4, topScore, topBox4, clsv, keepB);
    finalize_kernel<<<B_, 1024, 0, stream>>>(scores4, segKeys, segCnt, boxes4,
                                             topScore, topBox4, clsv, keepB, out);
}

// Round 7
// 174.493 us; speedup vs baseline: 1.0694x; 1.0694x over previous
//
#include <hip/hip_runtime.h>
#include <cstdint>
#include <cstddef>

// Problem constants (fixed by the reference)
#define B_      32
#define N_      8400
#define C_      80
#define NC      672000        // N_*C_
#define NCV4    168000        // NC/4
#define NBINS   4096
#define TOPK    1024
#define MAXDET  300
#define CANDCAP 4096
#define NSLICE  16
#define SLICE_V4 10500        // NCV4 / NSLICE
#define NBKT    8             // score bins 4088..4095 (all x in [0.998..1))
#define SEGB    64            // per-(batch,bucket,slice) cap (mean 10.25, 17 sigma)
#define BSORT   256           // per-bucket cap (mean 164, 7.2 sigma)

// Static stage threshold: score >= 4088/4096 = 0.998046875.
// Expected candidates/batch = 672000*8/4096 = 1312 (sd ~36). Bucket = bin-4088
// partitions candidates into 8 ORDER-DISJOINT groups (floor is monotone, float
// bits are monotone): buckets concatenated 7..0 == exact lax.top_k order
// (score desc, index asc via key low bits). Violating inputs take the exact
// in-kernel histogram fallback (never on bench input).
#define STAGE_THRESH 0.998046875f

// Workspace layout (bytes). Cross-kernel interface is COMPRESSED: class+valid
// packed to 1 byte/position (clsv), keep as 1 byte/position.
#define WS_SEGKEYS  0           // 32*8*16*64*8 = 2097152
#define WS_SEGCNT   2097152     // 32*8*16*4    = 16384
#define WS_TOPSCORE 2113536     // 32*1024*4    = 131072
#define WS_TOPBOX   2244608     // 32*1024*16   = 524288
#define WS_CLSV     2768896     // 32*1024*1    = 32768   (0x80|class, 0 = invalid)
#define WS_KEEP     2801664     // 32*1024*1    = 32768

// Output layout (float32, concatenated): boxes[32][300][4], scores[32][300],
// labels[32][300], n_valid[32]
#define OUT_SCORES  38400
#define OUT_LABELS  48000
#define OUT_NVALID  57600

// ---------------------------------------------------------------------------
// K1: single-pass filter+stage into PRIVATE per-(batch,bucket,slice) segments.
// key = (bits(v)<<32) | ~flat_idx. 8 LDS counters per block; plain global
// stores; no global atomics, no pre-zeroing (raw counts let K2 detect
// overflow -> fallback). Memory-bound: 86 MB read ~= 14.5 us (at roofline).
__global__ __launch_bounds__(256) void stage_kernel(const float4* __restrict__ scores4,
                                                    unsigned* __restrict__ segCnt,
                                                    unsigned long long* __restrict__ segKeys) {
    __shared__ unsigned lcnt[NBKT];
    int b = blockIdx.x, sl = blockIdx.y, tid = threadIdx.x;
    if (tid < NBKT) lcnt[tid] = 0;
    __syncthreads();
    const float4* s = scores4 + (size_t)b * NCV4 + (size_t)sl * SLICE_V4;
    for (int i = tid; i < SLICE_V4; i += 256) {
        float4 v = s[i];
        float c[4] = {v.x, v.y, v.z, v.w};
        unsigned flat0 = ((unsigned)sl * SLICE_V4 + (unsigned)i) * 4u;
        #pragma unroll
        for (int kc = 0; kc < 4; ++kc) {
            float x = (c[kc] > 0.001f) ? c[kc] : 0.0f;
            if (x >= STAGE_THRESH) {
                int bin = (int)(x * 4096.0f);             // exact: x * 2^12
                bin = bin > (NBINS - 1) ? (NBINS - 1) : bin;
                int bkt = bin - 4088;                      // 0..7
                unsigned p = atomicAdd(&lcnt[bkt], 1u);
                if (p < (unsigned)SEGB)
                    segKeys[(((size_t)(b * NBKT + bkt)) * NSLICE + sl) * SEGB + p] =
                        ((unsigned long long)__float_as_uint(x) << 32) |
                        (unsigned long long)(0xFFFFFFFFu - (flat0 + kc));
            }
        }
    }
    __syncthreads();
    if (tid < NBKT) segCnt[(b * NBKT + tid) * NSLICE + sl] = lcnt[tid];
}

// ---------------------------------------------------------------------------
// K2: one WAVE per (batch,bucket) — 256 parallel blocks. Fast path: gather the
// bucket's 16 slice-segments with all loads in flight, then RANK-AND-SCATTER:
// pos = bucket_base + #{greater keys in bucket}. Keys unique => exact
// permutation == lax.top_k order. Writes topScore/topBox + packed clsv byte;
// bkt-0 block also zeroes keep (1 KB, one uint4 store round). Invalid inputs:
// block (b,0) runs the exact histogram fallback (never on bench input).
__global__ __launch_bounds__(64) void select_kernel(
        const float4* __restrict__ scores4,
        const unsigned long long* __restrict__ segKeys,
        const unsigned* __restrict__ segCnt,
        const float4* __restrict__ boxes4,
        float* __restrict__ topScore,
        float4* __restrict__ topBox4,
        unsigned char* __restrict__ clsv,
        unsigned char* __restrict__ keepB) {
    __shared__ unsigned long long kbuf[CANDCAP];    // 32 KB (fast path uses 260)
    __shared__ unsigned scnt2[NBKT * NSLICE];       // all 128 segment counts
    __shared__ unsigned spref[NSLICE];              // own-bucket slice prefix
    __shared__ unsigned scnt;
    __shared__ int s_cut;
    int b = blockIdx.x, bkt = blockIdx.y, lane = threadIdx.x;

    // P0: load all 128 counts (2 coalesced loads/lane); every lane redundantly
    // computes bucket sums / validity / base from LDS broadcasts (lockstep).
    scnt2[lane]      = segCnt[b * NBKT * NSLICE + lane];
    scnt2[lane + 64] = segCnt[b * NBKT * NSLICE + lane + 64];
    __threadfence_block();
    unsigned M = 0, base = 0, n = 0; int valid = 1;
    #pragma unroll
    for (int t = 0; t < NBKT; ++t) {
        unsigned s2 = 0, mx = 0;
        #pragma unroll
        for (int sl = 0; sl < NSLICE; ++sl) {
            unsigned v = scnt2[t * NSLICE + sl];
            s2 += v; mx = v > mx ? v : mx;
        }
        if (mx > (unsigned)SEGB || s2 > (unsigned)BSORT) valid = 0;
        M += s2;
        if (t > bkt) base += s2;
        if (t == bkt) n = s2;
    }
    if (M < (unsigned)TOPK || M > (unsigned)CANDCAP) valid = 0;

    if (valid) {
        if (bkt == 0) {                              // zero keep BEFORE any return
            uint4 z; z.x = 0u; z.y = 0u; z.z = 0u; z.w = 0u;
            ((uint4*)(keepB + (size_t)b * TOPK))[lane] = z;
        }
        if (base >= (unsigned)TOPK || n == 0) return;
        // slice prefixes within own bucket
        if (lane < NSLICE) {
            unsigned acc = 0;
            for (int s2 = 0; s2 < lane; ++s2) acc += scnt2[bkt * NSLICE + s2];
            spref[lane] = acc;
        }
        __threadfence_block();
        // P1: gather — 16 segments concurrently, 4 lanes each (max load ILP)
        {
            int sl = lane & 15;
            int eo = lane >> 4;                      // 0..3
            unsigned cA = scnt2[bkt * NSLICE + sl];  // <= SEGB in valid path
            unsigned b0 = spref[sl];
            const unsigned long long* src =
                segKeys + (((size_t)(b * NBKT + bkt)) * NSLICE + sl) * SEGB;
            for (int e = eo; e < (int)cA; e += 4) kbuf[b0 + e] = src[e];
            if (lane < 4) kbuf[n + lane] = 0ull;     // pad for 4-wide rank loop
        }
        __threadfence_block();
        // P2: rank-and-scatter, 4 keys/lane, 4 independent reads per iter.
        int j0 = lane, j1 = lane + 64, j2 = lane + 128, j3 = lane + 192;
        unsigned long long k0 = (j0 < (int)n) ? kbuf[j0] : 0ull;
        unsigned long long k1 = (j1 < (int)n) ? kbuf[j1] : 0ull;
        unsigned long long k2 = (j2 < (int)n) ? kbuf[j2] : 0ull;
        unsigned long long k3 = (j3 < (int)n) ? kbuf[j3] : 0ull;
        unsigned r0 = 0, r1 = 0, r2 = 0, r3 = 0;
        for (unsigned i = 0; i < n; i += 4) {        // pad keys are 0: never >
            unsigned long long a = kbuf[i], b2 = kbuf[i + 1];
            unsigned long long c2 = kbuf[i + 2], d2 = kbuf[i + 3];
            r0 += (unsigned)(a > k0) + (unsigned)(b2 > k0) +
                  (unsigned)(c2 > k0) + (unsigned)(d2 > k0);
            r1 += (unsigned)(a > k1) + (unsigned)(b2 > k1) +
                  (unsigned)(c2 > k1) + (unsigned)(d2 > k1);
            r2 += (unsigned)(a > k2) + (unsigned)(b2 > k2) +
                  (unsigned)(c2 > k2) + (unsigned)(d2 > k2);
            r3 += (unsigned)(a > k3) + (unsigned)(b2 > k3) +
                  (unsigned)(c2 > k3) + (unsigned)(d2 > k3);
        }
        #pragma unroll
        for (int q = 0; q < 4; ++q) {
            int j = q == 0 ? j0 : q == 1 ? j1 : q == 2 ? j2 : j3;
            unsigned long long k = q == 0 ? k0 : q == 1 ? k1 : q == 2 ? k2 : k3;
            unsigned r = q == 0 ? r0 : q == 1 ? r1 : q == 2 ? r2 : r3;
            if (j < (int)n) {
                unsigned pos = base + r;
                if (pos < (unsigned)TOPK) {
                    float sc = __uint_as_float((unsigned)(k >> 32));
                    unsigned idx = 0xFFFFFFFFu - (unsigned)(k & 0xFFFFFFFFull);
                    if (idx >= (unsigned)NC) idx = 0;    // defensive
                    unsigned bi = idx / (unsigned)C_;
                    unsigned cl = idx - bi * (unsigned)C_;
                    topScore[b * TOPK + pos] = sc;
                    topBox4[b * TOPK + pos] = boxes4[(size_t)b * N_ + bi];
                    clsv[(size_t)b * TOPK + pos] = (unsigned char)(0x80u | cl);
                }
            }
        }
        return;
    }

    // ---- exact fallback: only block (b, bkt=0); single wave, fences only.
    if (bkt != 0) return;
    {
        uint4 z; z.x = 0u; z.y = 0u; z.z = 0u; z.w = 0u;
        ((uint4*)(keepB + (size_t)b * TOPK))[lane] = z;
    }
    unsigned* fh = (unsigned*)kbuf;      // aliases kbuf; dead before kbuf written
    for (int i2 = lane; i2 < NBINS; i2 += 64) fh[i2] = 0;
    if (lane == 0) scnt = 0;
    __threadfence_block();
    const float4* s = scores4 + (size_t)b * NCV4;
    for (int i2 = lane; i2 < NCV4; i2 += 64) {
        float4 v = s[i2];
        float c4[4] = {v.x, v.y, v.z, v.w};
        #pragma unroll
        for (int kc = 0; kc < 4; ++kc) {
            float x = (c4[kc] > 0.001f) ? c4[kc] : 0.0f;
            int bin = (int)(x * 4096.0f);
            bin = bin > (NBINS - 1) ? (NBINS - 1) : bin;
            atomicAdd(&fh[bin], 1u);
        }
    }
    __threadfence_block();
    if (lane == 0) {
        unsigned acc = 0; int cb = 0;
        for (int bin = NBINS - 1; bin >= 0; --bin) {
            acc += fh[bin];
            if (acc >= (unsigned)TOPK) { cb = bin; break; }
        }
        s_cut = cb;
    }
    __threadfence_block();               // lane0's fh reads done (lockstep)
    int cb = s_cut;
    for (int i2 = lane; i2 < NCV4; i2 += 64) {
        float4 v = s[i2];
        float c4[4] = {v.x, v.y, v.z, v.w};
        unsigned flat0 = (unsigned)i2 * 4u;
        #pragma unroll
        for (int kc = 0; kc < 4; ++kc) {
            float x = (c4[kc] > 0.001f) ? c4[kc] : 0.0f;
            int bin = (int)(x * 4096.0f);
            bin = bin > (NBINS - 1) ? (NBINS - 1) : bin;
            if (bin >= cb) {
                unsigned p = atomicAdd(&scnt, 1u);
                if (p < (unsigned)CANDCAP)
                    kbuf[p] = ((unsigned long long)__float_as_uint(x) << 32) |
                              (unsigned long long)(0xFFFFFFFFu - (flat0 + kc));
            }
        }
    }
    __threadfence_block();
    unsigned M2 = scnt; if (M2 > (unsigned)CANDCAP) M2 = CANDCAP;
    int S = (M2 <= 1024u) ? 1024 : (M2 <= 2048u ? 2048 : CANDCAP);
    for (int i2 = (int)M2 + lane; i2 < S; i2 += 64) kbuf[i2] = 0ull;
    __threadfence_block();
    for (int kk = 2; kk <= S; kk <<= 1) {
        for (int j = kk >> 1; j > 0; j >>= 1) {
            for (int t = lane; t < S; t += 64) {
                int l = t ^ j;
                if (l > t) {
                    unsigned long long a0 = kbuf[t], c0 = kbuf[l];
                    bool sw = ((t & kk) == 0) ? (a0 < c0) : (a0 > c0);
                    if (sw) { kbuf[t] = c0; kbuf[l] = a0; }
                }
            }
            __threadfence_block();
        }
    }
    for (int r = lane; r < TOPK; r += 64) {
        unsigned long long key = kbuf[r];
        float sc = __uint_as_float((unsigned)(key >> 32));
        unsigned idx = 0xFFFFFFFFu - (unsigned)(key & 0xFFFFFFFFull);
        if (idx >= (unsigned)NC) idx = 0;
        unsigned bi = idx / (unsigned)C_;
        unsigned cl = idx - bi * (unsigned)C_;
        topScore[b * TOPK + r] = sc;
        topBox4[b * TOPK + r] = boxes4[(size_t)b * N_ + bi];
        clsv[(size_t)b * TOPK + r] =
            (unsigned char)((sc > 0.001f ? 0x80u : 0u) | cl);
    }
}

// ---------------------------------------------------------------------------
// K3: per-(batch,class) greedy NMS, one 64-thread block per (b,c) — 2560-way
// parallel. Extraction is ONE coalesced 16 B/lane load of the packed class
// map (byte == 0x80|c <=> listed), per-lane popcount + 6-step shfl_up wave
// prefix, <=16-iter unrolled local place. Cross-class IoU is exactly 0
// (offset gap 4096 >> max box 640) => per-class greedy == the reference's
// global sequential loop. IoU in f32 with __fmul_rn (no FMA contraction).
#define CLS_CAP 256
__global__ __launch_bounds__(64) void nms_kernel(const unsigned char* __restrict__ clsv,
                                                 const float4* __restrict__ topBox4,
                                                 unsigned char* __restrict__ keepB) {
    __shared__ unsigned short spos[CLS_CAP];
    __shared__ float by1[CLS_CAP], bx1[CLS_CAP], by2[CLS_CAP], bx2[CLS_CAP];
    __shared__ float barea[CLS_CAP];
    __shared__ unsigned char sup[CLS_CAP];
    int b = blockIdx.x;
    int c = blockIdx.y;
    int lane = threadIdx.x;
    unsigned char* kp = keepB + (size_t)b * TOPK;

    // whole batch's class map: 16 consecutive bytes per lane, in registers
    uint4 w = ((const uint4*)(clsv + (size_t)b * TOPK))[lane];
    unsigned target = 0x80u | (unsigned)c;
    unsigned mmask = 0; int cnt = 0;
    #pragma unroll
    for (int t = 0; t < 16; ++t) {
        unsigned d = (t < 4) ? w.x : (t < 8) ? w.y : (t < 12) ? w.z : w.w;
        unsigned v = (d >> ((t & 3) * 8)) & 0xffu;
        if (v == target) { mmask |= (1u << t); ++cnt; }
    }
    // inclusive wave prefix over per-lane counts
    int x = cnt;
    #pragma unroll
    for (int o = 1; o < 64; o <<= 1) {
        int y = __shfl_up(x, o, 64);
        if (lane >= o) x += y;
    }
    int pre = x - cnt;
    int m = __shfl(x, 63, 64);
    // place own candidates: ascending (lane, t) == ascending pos == score desc
    int slot = pre;
    #pragma unroll
    for (int t = 0; t < 16; ++t) {
        if ((mmask >> t) & 1u) {
            if (slot < CLS_CAP) spos[slot] = (unsigned short)(lane * 16 + t);
            ++slot;
        }
    }
    int m2 = m < CLS_CAP ? m : CLS_CAP;
    __threadfence_block();
    // per-slot box setup (one random 16 B load per candidate, lane-parallel)
    float off = (float)c * 4096.0f;         // exact
    for (int j = lane; j < m2; j += 64) {
        int p = spos[j];
        float4 tb = topBox4[(size_t)b * TOPK + p];
        float y1 = tb.x + off, x1 = tb.y + off;
        float y2 = tb.z + off, x2 = tb.w + off;
        by1[j] = y1; bx1[j] = x1; by2[j] = y2; bx2[j] = x2;
        barea[j] = __fmul_rn((x2 - x1) + 1.0f, (y2 - y1) + 1.0f);
        sup[j] = 0;
    }
    __threadfence_block();
    int cur = 0;
    while (cur < m2) {
        // invariant: slot `cur` is unsuppressed -> kept
        if (lane == 0) kp[spos[cur]] = 1;
        float cy1 = by1[cur], cx1 = bx1[cur], cy2 = by2[cur], cx2 = bx2[cur];
        float carea = barea[cur];
        for (int j = cur + 1 + lane; j < m2; j += 64) {
            if (!sup[j]) {
                float yy1 = fmaxf(cy1, by1[j]), xx1 = fmaxf(cx1, bx1[j]);
                float yy2 = fminf(cy2, by2[j]), xx2 = fminf(cx2, bx2[j]);
                float w2 = fmaxf(0.0f, (xx2 - xx1) + 1.0f);
                float h2 = fmaxf(0.0f, (yy2 - yy1) + 1.0f);
                float inter = __fmul_rn(w2, h2);
                float denom = (carea + barea[j]) - inter;
                float iou = inter / denom;
                if (iou > 0.7f) sup[j] = 1;
            }
        }
        __threadfence_block();
        int nxt = m2;
        for (int j = cur + 1 + lane; j < m2; j += 64)
            if (!sup[j]) { nxt = j; break; }
        for (int o = 32; o > 0; o >>= 1) {
            int other = __shfl_xor(nxt, o, 64);
            nxt = nxt < other ? nxt : other;
        }
        cur = nxt;
    }
}

// ---------------------------------------------------------------------------
// K4: stable top-300 of final_scores: kept positions in order, then suppressed
// positions in order (score-0 ties break by lower index). keep is 0/1 uchar:
// ballot/popcount scan — 2 barriers. Labels derived from packed clsv.
__global__ __launch_bounds__(1024) void finalize_kernel(const float* __restrict__ topScore,
                                                        const float4* __restrict__ topBox4,
                                                        const unsigned char* __restrict__ clsv,
                                                        const unsigned char* __restrict__ keepB,
                                                        float* __restrict__ out) {
    __shared__ int wsum[16];
    __shared__ int sel[MAXDET];
    int b = blockIdx.x;
    int tid = threadIdx.x;
    int lane = tid & 63;
    int wave = tid >> 6;
    int kp = keepB[(size_t)b * TOPK + tid];
    unsigned long long mb = __ballot(kp != 0);
    int wpre = __popcll(mb & ((1ull << lane) - 1ull));
    if (lane == 0) wsum[wave] = __popcll(mb);
    __syncthreads();
    int wbase = 0, nk = 0;
    #pragma unroll
    for (int t = 0; t < 16; ++t) {
        int v = wsum[t];
        if (t < wave) wbase += v;
        nk += v;
    }
    int kexcl = wbase + wpre;    // exclusive kept rank
    int sexcl = tid - kexcl;     // exclusive suppressed rank
    if (kp) {
        if (kexcl < MAXDET) sel[kexcl] = tid;
    } else {
        int slot = nk + sexcl;
        if (slot < MAXDET) sel[slot] = tid;
    }
    __syncthreads();
    if (tid < MAXDET) {
        int p = sel[tid];
        float sc = (tid < nk) ? topScore[b * TOPK + p] : 0.0f;
        float4 tb = topBox4[(size_t)b * TOPK + p];
        float* ob = out + ((size_t)b * MAXDET + tid) * 4;
        ob[0] = tb.x; ob[1] = tb.y; ob[2] = tb.z; ob[3] = tb.w;
        out[OUT_SCORES + b * MAXDET + tid] = sc;
        out[OUT_LABELS + b * MAXDET + tid] =
            (float)(clsv[(size_t)b * TOPK + p] & 0x7f);
    }
    if (tid == 0) out[OUT_NVALID + b] = (float)(nk < MAXDET ? nk : MAXDET);
}

// ---------------------------------------------------------------------------
extern "C" void kernel_launch(void* const* d_in, const int* in_sizes, int n_in,
                              void* d_out, int out_size, void* d_ws, size_t ws_size,
                              hipStream_t stream) {
    const float* boxes  = (const float*)d_in[0];   // (32, 8400, 4)
    const float* scores = (const float*)d_in[1];   // (32, 8400, 80)
    float* out = (float*)d_out;
    char* ws = (char*)d_ws;

    unsigned long long* segKeys = (unsigned long long*)(ws + WS_SEGKEYS);
    unsigned* segCnt = (unsigned*)(ws + WS_SEGCNT);
    float* topScore = (float*)(ws + WS_TOPSCORE);
    float4* topBox4 = (float4*)(ws + WS_TOPBOX);
    unsigned char* clsv = (unsigned char*)(ws + WS_CLSV);
    unsigned char* keepB = (unsigned char*)(ws + WS_KEEP);

    const float4* scores4 = (const float4*)scores;
    const float4* boxes4  = (const float4*)boxes;

    stage_kernel<<<dim3(B_, NSLICE), 256, 0, stream>>>(scores4, segCnt, segKeys);
    select_kernel<<<dim3(B_, NBKT), 64, 0, stream>>>(scores4, segKeys, segCnt, boxes4,
                                                     topScore, topBox4, clsv, keepB);
    nms_kernel<<<dim3(B_, C_), 64, 0, stream>>>(clsv, topBox4, keepB);
    finalize_kernel<<<B_, 1024, 0, stream>>>(topScore, topBox4, clsv, keepB, out);
}